// Round 5
// baseline (152.957 us; speedup 1.0000x reference)
//
#include <hip/hip_runtime.h>
#include <hip/hip_bf16.h>

#define NROWS 8192
#define KDIM  256
#define NT    64                  // NROWS / 128
#define NBLK  (NT * (NT + 1) / 2) // 2080 upper-triangular 128x128 tiles
#define GRID  512                 // 2 blocks/CU; ~4 tiles per block

typedef __attribute__((ext_vector_type(4))) float f32x4;

// async global->LDS, 16B per lane; LDS dest is wave-uniform base + lane*16
#define GLD(gp, lp)                                                            \
  __builtin_amdgcn_global_load_lds(                                            \
      (const __attribute__((address_space(1))) void*)(gp),                     \
      (__attribute__((address_space(3))) void*)(lp), 16, 0, 0)

// ---------------------------------------------------------------------------
// Kernel 1: fp32 -> fp8 e4m3 convert + per-row sum of squares. One wave per
// row (64 lanes x float4 = 256), barrier-free. Wave 0 zeroes accumulators.
// ---------------------------------------------------------------------------
__global__ void prep_kernel(const float* __restrict__ samples,
                            unsigned char* __restrict__ sf8,
                            float* __restrict__ sq,
                            float* __restrict__ accg) {
  int t = threadIdx.x, lane = t & 63, wv = t >> 6;
  int row = blockIdx.x * 4 + wv;                    // grid 2048 x 256
  float4 v = ((const float4*)samples)[(size_t)row * 64 + lane];
  int pk0 = __builtin_amdgcn_cvt_pk_fp8_f32(v.x, v.y, 0, false);
  int pk1 = __builtin_amdgcn_cvt_pk_fp8_f32(v.z, v.w, 0, false);
  ((unsigned int*)sf8)[(size_t)row * 64 + lane] =
      (unsigned)(pk0 & 0xffff) | ((unsigned)pk1 << 16);
  float p = v.x * v.x + v.y * v.y + v.z * v.z + v.w * v.w;
#pragma unroll
  for (int off = 32; off; off >>= 1) p += __shfl_down(p, off);
  if (lane == 0) sq[row] = p;
  if (row == 0 && lane < 2) accg[lane] = 0.0f;
}

// decode triangular block index b -> (bi, bj), bi <= bj  (verified absmax 0.0)
__device__ inline void decode_tile(int b, int& bi, int& bj) {
  float disc = (2.0f * NT + 1.0f) * (2.0f * NT + 1.0f) - 8.0f * (float)b;
  bi = (int)(((2.0f * NT + 1.0f) - sqrtf(disc)) * 0.5f);
  if (bi < 0) bi = 0;
  if (bi > NT - 1) bi = NT - 1;
  while (bi > 0 && (bi * NT - bi * (bi - 1) / 2) > b) --bi;
  while (((bi + 1) * NT - (bi + 1) * bi / 2) <= b) ++bi;
  bj = bi + (b - (bi * NT - bi * (bi - 1) / 2));
}

// ---------------------------------------------------------------------------
// Kernel 2: persistent blocks walking CONTIGUOUS triangular indices (same bi
// for most of a block's ~4 tiles). A fragments live in REGISTERS (32 VGPRs,
// reloaded only when bi changes); LDS holds only double-buffered B
// (2x32 KB -> 2 blocks/CU, 16 waves/CU for cross-block pipe overlap).
// One barrier per tile; B prefetch flies behind MFMA+epilogue.
// ---------------------------------------------------------------------------
__global__ __launch_bounds__(512, 4) void pair_kernel(
    const unsigned char* __restrict__ sf8, const float* __restrict__ sq,
    const int* __restrict__ labels, float* __restrict__ accg) {

  __shared__ __align__(16) unsigned char Bs[2][32 * 1024];
  __shared__ float red[16];

  int t = threadIdx.x;
  int lane = t & 63;
  int w = t >> 6;               // 0..7
  int wm = w >> 1, wn = w & 1;  // wave tile: rows wm*32+, cols wn*64+
  int lr = lane >> 4, pc = lane & 15;  // staging: row-in-region, phys chunk
  int r = lane & 15;                   // fragment row within 16
  int ko = lane >> 4;                  // k-group: k-bytes ko*8
  int kq = ko >> 1, hf = (ko & 1) * 8;
  int q4 = ko * 4;

  // contiguous chunk of triangular indices: 2080/512 = 65/16 per block
  int t0 = (blockIdx.x * 65) >> 4;
  int t1 = ((blockIdx.x + 1) * 65) >> 4;
  int bi, bj;
  decode_tile(t0, bi, bj);

  // A fragments + A-side scalars in registers, valid for row-band `abi`
  long af[2][8];
  float sqa[8];
  int laa[8];
  auto loadA = [&](int bi_) {
#pragma unroll
    for (int i = 0; i < 2; i++) {
      const unsigned char* Ar =
          sf8 + (size_t)(bi_ * 128 + wm * 32 + i * 16 + r) * KDIM + ko * 8;
#pragma unroll
      for (int kc = 0; kc < 8; kc++) af[i][kc] = *(const long*)(Ar + kc * 32);
    }
#pragma unroll
    for (int i = 0; i < 2; i++)
#pragma unroll
      for (int q = 0; q < 4; q++) {
        int gr = bi_ * 128 + wm * 32 + i * 16 + q4 + q;
        sqa[i * 4 + q] = sq[gr];
        laa[i * 4 + q] = labels[gr];
      }
  };

  // stage B row-band bj_ into buffer buf: 32 regions x 1KB; XOR-16B swizzle
  // applied on the GLOBAL side (LDS dest stays wave-uniform + lane*16)
  auto stageB = [&](int bj_, int buf) {
#pragma unroll
    for (int p = 0; p < 4; ++p) {
      int region = p * 8 + w;
      int rr = region * 4 + lr;
      int c = pc ^ (rr & 15);
      GLD(sf8 + (size_t)(bj_ * 128 + rr) * KDIM + c * 16,
          &Bs[buf][region * 1024]);
    }
  };

  int abi = bi;
  loadA(bi);
  stageB(bj, 0);
  int cur = 0;
  float s1t = 0.f, s2t = 0.f;

  for (int tile = t0; tile < t1; ++tile) {
    __syncthreads();  // Bs[cur] staged (barrier's vmcnt drain covers GLDs)

    // B-side scalars for CURRENT tile (issued before prefetch GLDs)
    float sqb[4];
    int lab[4];
#pragma unroll
    for (int j = 0; j < 4; j++) {
      int gc = bj * 128 + wn * 64 + j * 16 + r;
      sqb[j] = sq[gc];
      lab[j] = labels[gc];
    }

    if (bi != abi) { loadA(bi); abi = bi; }  // rare: row-band transition

    int nbi = bi, nbj = bj + 1;
    if (nbj == NT) { ++nbi; nbj = nbi; }
    if (tile + 1 < t1) stageB(nbj, cur ^ 1);  // async prefetch, other buffer

    // ---- barrier-free MFMA phase: B frags from LDS, A from registers ----
    f32x4 acc[2][4];
#pragma unroll
    for (int i = 0; i < 2; i++)
#pragma unroll
      for (int j = 0; j < 4; j++) acc[i][j] = (f32x4){0.f, 0.f, 0.f, 0.f};

#pragma unroll
    for (int kc = 0; kc < 8; ++kc) {
      long bfr[4];
#pragma unroll
      for (int j = 0; j < 4; j++) {
        int n = wn * 64 + j * 16 + r;
        bfr[j] =
            *(const long*)(&Bs[cur][n * 256 + (((kc * 2 + kq) ^ r) * 16) + hf]);
      }
#pragma unroll
      for (int i = 0; i < 2; i++)
#pragma unroll
        for (int j = 0; j < 4; j++)
          acc[i][j] = __builtin_amdgcn_mfma_f32_16x16x32_fp8_fp8(
              af[i][kc], bfr[j], acc[i][j], 0, 0, 0);
    }

    // ---- epilogue: gram -> S -> masked sums, accumulate in registers ----
    // C/D layout: col = lane&15 (n), row = (lane>>4)*4 + reg (m)
    float s1 = 0.f, s2 = 0.f;
#pragma unroll
    for (int j = 0; j < 4; j++) {
#pragma unroll
      for (int i = 0; i < 2; i++) {
#pragma unroll
        for (int q = 0; q < 4; q++) {
          float S = (sqa[i * 4 + q] + sqb[j] - 2.0f * acc[i][j][q]) *
                    (1.0f / 256.0f);
          if (laa[i * 4 + q] == lab[j]) s1 += S;
          else                          s2 += fmaxf(0.f, 1.f - S);
        }
      }
    }
    float wt = (bi == bj) ? 1.0f : 2.0f;  // off-diagonal tiles count twice
    s1t += wt * s1;
    s2t += wt * s2;

    bi = nbi; bj = nbj; cur ^= 1;
  }

  // ---- once per block: reduce 8 waves, 2 atomics ----
#pragma unroll
  for (int off = 32; off; off >>= 1) {
    s1t += __shfl_down(s1t, off);
    s2t += __shfl_down(s2t, off);
  }
  if (lane == 0) { red[w] = s1t; red[8 + w] = s2t; }
  __syncthreads();
  if (t == 0) {
    float a = 0.f, b2 = 0.f;
#pragma unroll
    for (int k = 0; k < 8; k++) { a += red[k]; b2 += red[8 + k]; }
    atomicAdd(&accg[0], a);
    atomicAdd(&accg[1], b2);
  }
}

// ---------------------------------------------------------------------------
// Kernel 3: final scalar
// ---------------------------------------------------------------------------
__global__ void finalize_kernel(const float* __restrict__ accg,
                                float* __restrict__ out) {
  out[0] = 10.0f * (accg[0] + accg[1]) *
           (1.0f / ((float)NROWS * (float)NROWS));
}

extern "C" void kernel_launch(void* const* d_in, const int* in_sizes, int n_in,
                              void* d_out, int out_size, void* d_ws,
                              size_t ws_size, hipStream_t stream) {
  // inputs: 0=merged (unused), 1=input1 (unused), 2=samples, 3=labels
  const float* samples = (const float*)d_in[2];
  const int*   labels  = (const int*)d_in[3];

  char* ws = (char*)d_ws;
  unsigned char* sf8 = (unsigned char*)ws;                        // 2 MiB fp8
  float* sq   = (float*)(ws + (size_t)NROWS * KDIM);              // 32 KiB
  float* accg = (float*)(ws + (size_t)NROWS * KDIM + NROWS * 4);  // 8 B
  float* out  = (float*)d_out;

  prep_kernel<<<NROWS / 4, 256, 0, stream>>>(samples, sf8, sq, accg);
  pair_kernel<<<GRID, 512, 0, stream>>>(sf8, sq, labels, accg);
  finalize_kernel<<<1, 1, 0, stream>>>(accg, out);
}

// Round 6
// 150.021 us; speedup vs baseline: 1.0196x; 1.0196x over previous
//
#include <hip/hip_runtime.h>
#include <hip/hip_bf16.h>

#define NROWS 8192
#define KDIM  256
#define NT    64                  // NROWS / 128
#define NBLK  (NT * (NT + 1) / 2) // 2080 upper-triangular 128x128 tiles
#define GRID  512                 // 2 blocks/CU; ~4 tiles per block

typedef __attribute__((ext_vector_type(4))) float f32x4;

// async global->LDS, 16B per lane; LDS dest is wave-uniform base + lane*16
#define GLD(gp, lp)                                                            \
  __builtin_amdgcn_global_load_lds(                                            \
      (const __attribute__((address_space(1))) void*)(gp),                     \
      (__attribute__((address_space(3))) void*)(lp), 16, 0, 0)

// ---------------------------------------------------------------------------
// Kernel 1: fp32 -> fp8 e4m3 convert + per-row sum of squares. One wave per
// row (64 lanes x float4 = 256), barrier-free. Wave 0 zeroes accumulators.
// ---------------------------------------------------------------------------
__global__ void prep_kernel(const float* __restrict__ samples,
                            unsigned char* __restrict__ sf8,
                            float* __restrict__ sq,
                            float* __restrict__ accg) {
  int t = threadIdx.x, lane = t & 63, wv = t >> 6;
  int row = blockIdx.x * 4 + wv;                    // grid 2048 x 256
  float4 v = ((const float4*)samples)[(size_t)row * 64 + lane];
  int pk0 = __builtin_amdgcn_cvt_pk_fp8_f32(v.x, v.y, 0, false);
  int pk1 = __builtin_amdgcn_cvt_pk_fp8_f32(v.z, v.w, 0, false);
  ((unsigned int*)sf8)[(size_t)row * 64 + lane] =
      (unsigned)(pk0 & 0xffff) | ((unsigned)pk1 << 16);
  float p = v.x * v.x + v.y * v.y + v.z * v.z + v.w * v.w;
#pragma unroll
  for (int off = 32; off; off >>= 1) p += __shfl_down(p, off);
  if (lane == 0) sq[row] = p;
  if (row == 0 && lane < 2) accg[lane] = 0.0f;
}

// decode triangular block index b -> (bi, bj), bi <= bj  (verified absmax 0.0)
__device__ inline void decode_tile(int b, int& bi, int& bj) {
  float disc = (2.0f * NT + 1.0f) * (2.0f * NT + 1.0f) - 8.0f * (float)b;
  bi = (int)(((2.0f * NT + 1.0f) - sqrtf(disc)) * 0.5f);
  if (bi < 0) bi = 0;
  if (bi > NT - 1) bi = NT - 1;
  while (bi > 0 && (bi * NT - bi * (bi - 1) / 2) > b) --bi;
  while (((bi + 1) * NT - (bi + 1) * bi / 2) <= b) ++bi;
  bj = bi + (b - (bi * NT - bi * (bi - 1) / 2));
}

// A fragments + A-side scalars -> registers (straight-line, no lambda: the
// round-5 lambda capture forced af into scratch -> 25 MB spill traffic)
#define LOAD_A(BI)                                                             \
  {                                                                            \
    _Pragma("unroll") for (int i = 0; i < 2; i++) {                            \
      const unsigned char* Ar =                                                \
          sf8 + (size_t)((BI) * 128 + wm * 32 + i * 16 + r) * KDIM + ko * 8;   \
      _Pragma("unroll") for (int kc = 0; kc < 8; kc++)                         \
          af[i][kc] = *(const long*)(Ar + kc * 32);                            \
    }                                                                          \
    _Pragma("unroll") for (int i = 0; i < 2; i++)                              \
        _Pragma("unroll") for (int q = 0; q < 4; q++) {                        \
      int gr = (BI) * 128 + wm * 32 + i * 16 + q4 + q;                         \
      sqa[i * 4 + q] = sq[gr];                                                 \
      laa[i * 4 + q] = labels[gr];                                             \
    }                                                                          \
  }

// stage B row-band into buffer: 32 regions x 1KB; XOR-16B swizzle applied on
// the GLOBAL side (LDS dest stays wave-uniform + lane*16)
#define STAGE_B(BJ, BUF)                                                       \
  {                                                                            \
    _Pragma("unroll") for (int p = 0; p < 4; ++p) {                            \
      int region = p * 8 + w;                                                  \
      int rr = region * 4 + lr;                                                \
      int c = pc ^ (rr & 15);                                                  \
      GLD(sf8 + (size_t)((BJ) * 128 + rr) * KDIM + c * 16,                     \
          &Bs[BUF][region * 1024]);                                            \
    }                                                                          \
  }

// ---------------------------------------------------------------------------
// Kernel 2: persistent blocks, contiguous triangular walk (bi changes rarely;
// A fragments live in registers). LDS = EXACTLY 64 KB (double-buffered B) so
// 2 blocks/CU co-schedule; one barrier per tile; B prefetch flies behind MFMA.
// ---------------------------------------------------------------------------
__global__ __launch_bounds__(512, 4) void pair_kernel(
    const unsigned char* __restrict__ sf8, const float* __restrict__ sq,
    const int* __restrict__ labels, float* __restrict__ accg) {

  __shared__ __align__(16) unsigned char Bs[2][32 * 1024];  // 65536 B total

  int t = threadIdx.x;
  int lane = t & 63;
  int w = t >> 6;               // 0..7
  int wm = w >> 1, wn = w & 1;  // wave tile: rows wm*32+, cols wn*64+
  int lr = lane >> 4, pc = lane & 15;  // staging: row-in-region, phys chunk
  int r = lane & 15;                   // fragment row within 16
  int ko = lane >> 4;                  // k-group: k-bytes ko*8
  int kq = ko >> 1, hf = (ko & 1) * 8;
  int q4 = ko * 4;

  // contiguous chunk of triangular indices: 2080/512 = 65/16 per block
  int t0 = (blockIdx.x * 65) >> 4;
  int t1 = ((blockIdx.x + 1) * 65) >> 4;
  int bi, bj;
  decode_tile(t0, bi, bj);

  long af[2][8];
  float sqa[8];
  int laa[8];

  int abi = bi;
  LOAD_A(bi);
  STAGE_B(bj, 0);
  int cur = 0;
  float s1t = 0.f, s2t = 0.f;

  for (int tile = t0; tile < t1; ++tile) {
    __syncthreads();  // Bs[cur] staged (barrier's vmcnt drain covers GLDs)

    // B-side scalars for CURRENT tile (issued before prefetch GLDs)
    float sqb[4];
    int lab[4];
#pragma unroll
    for (int j = 0; j < 4; j++) {
      int gc = bj * 128 + wn * 64 + j * 16 + r;
      sqb[j] = sq[gc];
      lab[j] = labels[gc];
    }

    if (bi != abi) { LOAD_A(bi); abi = bi; }  // rare: row-band transition

    int nbi = bi, nbj = bj + 1;
    if (nbj == NT) { ++nbi; nbj = nbi; }
    if (tile + 1 < t1) STAGE_B(nbj, cur ^ 1);  // async prefetch, other buffer

    // ---- barrier-free MFMA phase: B frags from LDS, A from registers ----
    f32x4 acc[2][4];
#pragma unroll
    for (int i = 0; i < 2; i++)
#pragma unroll
      for (int j = 0; j < 4; j++) acc[i][j] = (f32x4){0.f, 0.f, 0.f, 0.f};

#pragma unroll
    for (int kc = 0; kc < 8; ++kc) {
      long bfr[4];
#pragma unroll
      for (int j = 0; j < 4; j++) {
        int n = wn * 64 + j * 16 + r;
        bfr[j] =
            *(const long*)(&Bs[cur][n * 256 + (((kc * 2 + kq) ^ r) * 16) + hf]);
      }
#pragma unroll
      for (int i = 0; i < 2; i++)
#pragma unroll
        for (int j = 0; j < 4; j++)
          acc[i][j] = __builtin_amdgcn_mfma_f32_16x16x32_fp8_fp8(
              af[i][kc], bfr[j], acc[i][j], 0, 0, 0);
    }

    // ---- epilogue: gram -> S -> masked sums, accumulate in registers ----
    // C/D layout: col = lane&15 (n), row = (lane>>4)*4 + reg (m)
    float s1 = 0.f, s2 = 0.f;
#pragma unroll
    for (int j = 0; j < 4; j++) {
#pragma unroll
      for (int i = 0; i < 2; i++) {
#pragma unroll
        for (int q = 0; q < 4; q++) {
          float S = (sqa[i * 4 + q] + sqb[j] - 2.0f * acc[i][j][q]) *
                    (1.0f / 256.0f);
          if (laa[i * 4 + q] == lab[j]) s1 += S;
          else                          s2 += fmaxf(0.f, 1.f - S);
        }
      }
    }
    float wt = (bi == bj) ? 1.0f : 2.0f;  // off-diagonal tiles count twice
    s1t += wt * s1;
    s2t += wt * s2;

    bi = nbi; bj = nbj; cur ^= 1;
  }

  // ---- once per block: reduce 8 waves (reusing Bs as scratch), 2 atomics ----
#pragma unroll
  for (int off = 32; off; off >>= 1) {
    s1t += __shfl_down(s1t, off);
    s2t += __shfl_down(s2t, off);
  }
  __syncthreads();  // all waves done reading Bs; safe to reuse as scratch
  float* red = (float*)&Bs[0][0];
  if (lane == 0) { red[w] = s1t; red[8 + w] = s2t; }
  __syncthreads();
  if (t == 0) {
    float a = 0.f, b2 = 0.f;
#pragma unroll
    for (int k = 0; k < 8; k++) { a += red[k]; b2 += red[8 + k]; }
    atomicAdd(&accg[0], a);
    atomicAdd(&accg[1], b2);
  }
}

// ---------------------------------------------------------------------------
// Kernel 3: final scalar
// ---------------------------------------------------------------------------
__global__ void finalize_kernel(const float* __restrict__ accg,
                                float* __restrict__ out) {
  out[0] = 10.0f * (accg[0] + accg[1]) *
           (1.0f / ((float)NROWS * (float)NROWS));
}

extern "C" void kernel_launch(void* const* d_in, const int* in_sizes, int n_in,
                              void* d_out, int out_size, void* d_ws,
                              size_t ws_size, hipStream_t stream) {
  // inputs: 0=merged (unused), 1=input1 (unused), 2=samples, 3=labels
  const float* samples = (const float*)d_in[2];
  const int*   labels  = (const int*)d_in[3];

  char* ws = (char*)d_ws;
  unsigned char* sf8 = (unsigned char*)ws;                        // 2 MiB fp8
  float* sq   = (float*)(ws + (size_t)NROWS * KDIM);              // 32 KiB
  float* accg = (float*)(ws + (size_t)NROWS * KDIM + NROWS * 4);  // 8 B
  float* out  = (float*)d_out;

  prep_kernel<<<NROWS / 4, 256, 0, stream>>>(samples, sf8, sq, accg);
  pair_kernel<<<GRID, 512, 0, stream>>>(sf8, sq, labels, accg);
  finalize_kernel<<<1, 1, 0, stream>>>(accg, out);
}

// Round 7
// 143.656 us; speedup vs baseline: 1.0647x; 1.0443x over previous
//
#include <hip/hip_runtime.h>
#include <hip/hip_bf16.h>

#define NROWS 8192
#define KDIM  256
#define NT    64                  // NROWS / 128
#define NBLK  (NT * (NT + 1) / 2) // 2080 upper-triangular 128x128 tiles
#define GRID  512                 // 2 blocks/CU; ~4 tiles per block

typedef __attribute__((ext_vector_type(4))) float f32x4;

// async global->LDS, 16B per lane; LDS dest is wave-uniform base + lane*16
#define GLD(gp, lp)                                                            \
  __builtin_amdgcn_global_load_lds(                                            \
      (const __attribute__((address_space(1))) void*)(gp),                     \
      (__attribute__((address_space(3))) void*)(lp), 16, 0, 0)

// ---------------------------------------------------------------------------
// Kernel 1: fp32 -> fp8 e4m3 convert + per-row sum of squares. One wave per
// row (64 lanes x float4 = 256), barrier-free. Wave 0 zeroes accumulators.
// ---------------------------------------------------------------------------
__global__ void prep_kernel(const float* __restrict__ samples,
                            unsigned char* __restrict__ sf8,
                            float* __restrict__ sq,
                            float* __restrict__ accg) {
  int t = threadIdx.x, lane = t & 63, wv = t >> 6;
  int row = blockIdx.x * 4 + wv;                    // grid 2048 x 256
  float4 v = ((const float4*)samples)[(size_t)row * 64 + lane];
  int pk0 = __builtin_amdgcn_cvt_pk_fp8_f32(v.x, v.y, 0, false);
  int pk1 = __builtin_amdgcn_cvt_pk_fp8_f32(v.z, v.w, 0, false);
  ((unsigned int*)sf8)[(size_t)row * 64 + lane] =
      (unsigned)(pk0 & 0xffff) | ((unsigned)pk1 << 16);
  float p = v.x * v.x + v.y * v.y + v.z * v.z + v.w * v.w;
#pragma unroll
  for (int off = 32; off; off >>= 1) p += __shfl_down(p, off);
  if (lane == 0) sq[row] = p;
  if (row == 0 && lane < 2) accg[lane] = 0.0f;
}

// decode triangular block index b -> (bi, bj), bi <= bj  (verified absmax 0.0)
__device__ inline void decode_tile(int b, int& bi, int& bj) {
  float disc = (2.0f * NT + 1.0f) * (2.0f * NT + 1.0f) - 8.0f * (float)b;
  bi = (int)(((2.0f * NT + 1.0f) - sqrtf(disc)) * 0.5f);
  if (bi < 0) bi = 0;
  if (bi > NT - 1) bi = NT - 1;
  while (bi > 0 && (bi * NT - bi * (bi - 1) / 2) > b) --bi;
  while (((bi + 1) * NT - (bi + 1) * bi / 2) <= b) ++bi;
  bj = bi + (b - (bi * NT - bi * (bi - 1) / 2));
}

// A fragments + A-side scalars -> registers (straight-line unrolled)
#define LOAD_A(BI)                                                             \
  {                                                                            \
    _Pragma("unroll") for (int i = 0; i < 2; i++) {                            \
      const unsigned char* Ar =                                                \
          sf8 + (size_t)((BI) * 128 + wm * 32 + i * 16 + r) * KDIM + ko * 8;   \
      _Pragma("unroll") for (int kc = 0; kc < 8; kc++)                         \
          af[i][kc] = *(const long*)(Ar + kc * 32);                            \
    }                                                                          \
    _Pragma("unroll") for (int i = 0; i < 2; i++)                              \
        _Pragma("unroll") for (int q = 0; q < 4; q++) {                        \
      int gr = (BI) * 128 + wm * 32 + i * 16 + q4 + q;                         \
      sqa[i * 4 + q] = sq[gr];                                                 \
      laa[i * 4 + q] = labels[gr];                                             \
    }                                                                          \
  }

// stage B row-band into buffer: 32 regions x 1KB; XOR-16B swizzle applied on
// the GLOBAL side (LDS dest stays wave-uniform + lane*16)
#define STAGE_B(BJ, BUF)                                                       \
  {                                                                            \
    _Pragma("unroll") for (int p = 0; p < 4; ++p) {                            \
      int region = p * 8 + w;                                                  \
      int rr = region * 4 + lr;                                                \
      int c = pc ^ (rr & 15);                                                  \
      GLD(sf8 + (size_t)((BJ) * 128 + rr) * KDIM + c * 16,                     \
          &Bs[BUF][region * 1024]);                                            \
    }                                                                          \
  }

// ---------------------------------------------------------------------------
// Kernel 2: persistent blocks, contiguous triangular walk (bi changes rarely;
// A fragments live in registers). LDS = EXACTLY 64 KB (double-buffered B) so
// 2 blocks/CU can co-schedule. NOTE: no min-waves launch-bounds arg — with
// 512 threads, (512,4) capped arch VGPRs at 64 and spilled af -> 20 MB
// scratch traffic (rounds 5-6). Demand is ~108 regs; let the allocator pick.
// ---------------------------------------------------------------------------
__global__ __launch_bounds__(512) void pair_kernel(
    const unsigned char* __restrict__ sf8, const float* __restrict__ sq,
    const int* __restrict__ labels, float* __restrict__ accg) {

  __shared__ __align__(16) unsigned char Bs[2][32 * 1024];  // 65536 B total

  int t = threadIdx.x;
  int lane = t & 63;
  int w = t >> 6;               // 0..7
  int wm = w >> 1, wn = w & 1;  // wave tile: rows wm*32+, cols wn*64+
  int lr = lane >> 4, pc = lane & 15;  // staging: row-in-region, phys chunk
  int r = lane & 15;                   // fragment row within 16
  int ko = lane >> 4;                  // k-group: k-bytes ko*8
  int kq = ko >> 1, hf = (ko & 1) * 8;
  int q4 = ko * 4;

  // contiguous chunk of triangular indices: 2080/512 = 65/16 per block
  int t0 = (blockIdx.x * 65) >> 4;
  int t1 = ((blockIdx.x + 1) * 65) >> 4;
  int bi, bj;
  decode_tile(t0, bi, bj);

  long af[2][8];
  float sqa[8];
  int laa[8];

  int abi = bi;
  LOAD_A(bi);
  STAGE_B(bj, 0);
  int cur = 0;
  float s1t = 0.f, s2t = 0.f;

  for (int tile = t0; tile < t1; ++tile) {
    __syncthreads();  // Bs[cur] staged (barrier's vmcnt drain covers GLDs)

    // B-side scalars for CURRENT tile (issued before prefetch GLDs so the
    // epilogue's vmcnt wait does not drain the prefetch)
    float sqb[4];
    int lab[4];
#pragma unroll
    for (int j = 0; j < 4; j++) {
      int gc = bj * 128 + wn * 64 + j * 16 + r;
      sqb[j] = sq[gc];
      lab[j] = labels[gc];
    }

    if (bi != abi) { LOAD_A(bi); abi = bi; }  // rare: row-band transition

    int nbi = bi, nbj = bj + 1;
    if (nbj == NT) { ++nbi; nbj = nbi; }
    if (tile + 1 < t1) STAGE_B(nbj, cur ^ 1);  // async prefetch, other buffer

    // ---- barrier-free MFMA phase: B frags from LDS, A from registers ----
    f32x4 acc[2][4];
#pragma unroll
    for (int i = 0; i < 2; i++)
#pragma unroll
      for (int j = 0; j < 4; j++) acc[i][j] = (f32x4){0.f, 0.f, 0.f, 0.f};

#pragma unroll
    for (int kc = 0; kc < 8; ++kc) {
      long bfr[4];
#pragma unroll
      for (int j = 0; j < 4; j++) {
        int n = wn * 64 + j * 16 + r;
        bfr[j] =
            *(const long*)(&Bs[cur][n * 256 + (((kc * 2 + kq) ^ r) * 16) + hf]);
      }
#pragma unroll
      for (int i = 0; i < 2; i++)
#pragma unroll
        for (int j = 0; j < 4; j++)
          acc[i][j] = __builtin_amdgcn_mfma_f32_16x16x32_fp8_fp8(
              af[i][kc], bfr[j], acc[i][j], 0, 0, 0);
    }

    // ---- epilogue: gram -> S -> masked sums, accumulate in registers ----
    // C/D layout: col = lane&15 (n), row = (lane>>4)*4 + reg (m)
    float s1 = 0.f, s2 = 0.f;
#pragma unroll
    for (int j = 0; j < 4; j++) {
#pragma unroll
      for (int i = 0; i < 2; i++) {
#pragma unroll
        for (int q = 0; q < 4; q++) {
          float S = (sqa[i * 4 + q] + sqb[j] - 2.0f * acc[i][j][q]) *
                    (1.0f / 256.0f);
          if (laa[i * 4 + q] == lab[j]) s1 += S;
          else                          s2 += fmaxf(0.f, 1.f - S);
        }
      }
    }
    float wt = (bi == bj) ? 1.0f : 2.0f;  // off-diagonal tiles count twice
    s1t += wt * s1;
    s2t += wt * s2;

    bi = nbi; bj = nbj; cur ^= 1;
  }

  // ---- once per block: reduce 8 waves (reusing Bs as scratch), 2 atomics ----
#pragma unroll
  for (int off = 32; off; off >>= 1) {
    s1t += __shfl_down(s1t, off);
    s2t += __shfl_down(s2t, off);
  }
  __syncthreads();  // all waves done reading Bs; safe to reuse as scratch
  float* red = (float*)&Bs[0][0];
  if (lane == 0) { red[w] = s1t; red[8 + w] = s2t; }
  __syncthreads();
  if (t == 0) {
    float a = 0.f, b2 = 0.f;
#pragma unroll
    for (int k = 0; k < 8; k++) { a += red[k]; b2 += red[8 + k]; }
    atomicAdd(&accg[0], a);
    atomicAdd(&accg[1], b2);
  }
}

// ---------------------------------------------------------------------------
// Kernel 3: final scalar
// ---------------------------------------------------------------------------
__global__ void finalize_kernel(const float* __restrict__ accg,
                                float* __restrict__ out) {
  out[0] = 10.0f * (accg[0] + accg[1]) *
           (1.0f / ((float)NROWS * (float)NROWS));
}

extern "C" void kernel_launch(void* const* d_in, const int* in_sizes, int n_in,
                              void* d_out, int out_size, void* d_ws,
                              size_t ws_size, hipStream_t stream) {
  // inputs: 0=merged (unused), 1=input1 (unused), 2=samples, 3=labels
  const float* samples = (const float*)d_in[2];
  const int*   labels  = (const int*)d_in[3];

  char* ws = (char*)d_ws;
  unsigned char* sf8 = (unsigned char*)ws;                        // 2 MiB fp8
  float* sq   = (float*)(ws + (size_t)NROWS * KDIM);              // 32 KiB
  float* accg = (float*)(ws + (size_t)NROWS * KDIM + NROWS * 4);  // 8 B
  float* out  = (float*)d_out;

  prep_kernel<<<NROWS / 4, 256, 0, stream>>>(samples, sf8, sq, accg);
  pair_kernel<<<GRID, 512, 0, stream>>>(sf8, sq, labels, accg);
  finalize_kernel<<<1, 1, 0, stream>>>(accg, out);
}